// Round 6
// baseline (153.720 us; speedup 1.0000x reference)
//
#include <hip/hip_runtime.h>

// MyConvT: masked ConvTranspose2d, B=8, Cin=192, Cout=128, 64x64 -> 128x128,
// K=5, S=2, P=2, OP=1.  out = pooled_mask ? (convT(x,w) + bias) : 0
// Round 5: cache-direct MFMA (no LDS, no barriers in the K-loop).
//   Block = (b, oy-pair), 4 waves = (coh, oys). Wave = 64co x 2oh x 128ow,
//   acc[2ph][2pw][4mi][4ti] = 256 VGPR. Every wave MFMAs every tap (zero
//   parity idleness); 256 identical blocks = 1/CU, single dispatch round.
//   A-frags (w) stream from L2; B-frags (x) from L1 (33.8KB/round working set),
//   with taps grouped by (plane a, shift o) so 4 taps share one bf set
//   (x reads cut 200->72 per round). af prefetch 1 tap ahead, bf 1 group
//   ahead; compiler inserts exact counted waitcnts. Coalesced f32x2 stores.

#define NB   8
#define CIN  192
#define COUT 128
#define HH   64
#define WW   64
#define OHH  128
#define OWW  128
#define MH   132
#define MW   132

#define XPLN_G   (66 * CIN)              // shorts per global x plane (12672)
#define WT_TAP   (COUT * CIN)            // 24576 shorts per tap

typedef short bf16x8 __attribute__((ext_vector_type(8)));
typedef float f32x4  __attribute__((ext_vector_type(4)));
typedef float f32x2  __attribute__((ext_vector_type(2)));

static __device__ __forceinline__ unsigned short f2bf(float f) {
  union { float f; unsigned int u; } a; a.f = f;
  return (unsigned short)((a.u + 0x7fffu + ((a.u >> 16) & 1u)) >> 16);   // RNE
}

// ---------------- mask 5x5 any-pool -> byte map [B][OH][OW] ----------------
__global__ __launch_bounds__(256) void pool_mask_k(const int* __restrict__ mask,
                                                   unsigned char* __restrict__ many) {
  int idx = blockIdx.x * 256 + threadIdx.x;
  if (idx >= NB * OHH * OWW) return;
  int ow = idx & (OWW - 1);
  int oh = (idx >> 7) & (OHH - 1);
  int b  = idx >> 14;
  const int* mp = mask + (b * MH + oh) * MW + ow;
  int any = 0;
  #pragma unroll
  for (int i = 0; i < 5; ++i)
    #pragma unroll
    for (int j = 0; j < 5; ++j)
      any |= mp[i * MW + j];
  many[idx] = (any != 0) ? 1 : 0;
}

// x transpose: [b][ci][iy][ix] f32 -> [b][iyH 0..65][ixm 0..65][ci 192] bf16
// iyH = iy+1 (planes 0,65 = zero halo); ixm = ix+1 (cols 0,65 = zero halo).
__global__ __launch_bounds__(256) void xpose_k(const float* __restrict__ x,
                                               unsigned short* __restrict__ xt) {
  const int b = blockIdx.x / 66, iyH = blockIdx.x % 66;
  const int lane = threadIdx.x & 63, wv = threadIdx.x >> 6;
  unsigned short* pl = xt + (size_t)(b * 66 + iyH) * XPLN_G;

  if (iyH == 0 || iyH == 65) {                       // zero halo plane
    for (int i = threadIdx.x; i < XPLN_G / 8; i += 256)
      *(uint4*)(pl + i * 8) = make_uint4(0, 0, 0, 0);
    return;
  }
  const int iy = iyH - 1;
  if (threadIdx.x < 48) {                            // zero halo cols (rows 0,65)
    int row = threadIdx.x < 24 ? 0 : 65, ch = threadIdx.x % 24;
    *(uint4*)(pl + row * CIN + ch * 8) = make_uint4(0, 0, 0, 0);
  }
  #pragma unroll
  for (int k = 0; k < 6; ++k) {
    int ci0 = wv * 48 + k * 8;
    unsigned short p[8];
    #pragma unroll
    for (int e = 0; e < 8; ++e)
      p[e] = f2bf(x[(((size_t)b * CIN + ci0 + e) * HH + iy) * WW + lane]);
    uint4 v;
    v.x = (unsigned)p[0] | ((unsigned)p[1] << 16);
    v.y = (unsigned)p[2] | ((unsigned)p[3] << 16);
    v.z = (unsigned)p[4] | ((unsigned)p[5] << 16);
    v.w = (unsigned)p[6] | ((unsigned)p[7] << 16);
    *(uint4*)(pl + (size_t)(1 + lane) * CIN + ci0) = v;
  }
}

// ---- w repack: [ci][co][kh][kw] f32 -> [kh*5+kw][co][ci 192] bf16 ----
__global__ __launch_bounds__(256) void wpack_k(const float* __restrict__ w,
                                               unsigned short* __restrict__ wt) {
  int idx = blockIdx.x * 256 + threadIdx.x;
  if (idx >= CIN * COUT) return;
  int ci = idx % CIN;
  int co = idx / CIN;
  const float* src = w + (size_t)(ci * COUT + co) * 25;
  #pragma unroll
  for (int t = 0; t < 25; ++t)
    wt[(size_t)t * WT_TAP + co * CIN + ci] = f2bf(src[t]);
}

// ------------------------------ main kernel --------------------------------
#define LOAD_AF(set, tapid, xoff)                                              \
  {                                                                            \
    _Pragma("unroll") for (int k2 = 0; k2 < 2; ++k2)                           \
      _Pragma("unroll") for (int mi = 0; mi < 4; ++mi)                         \
        afr[set][k2][mi] = *(const bf16x8*)(wlane +                            \
            (size_t)((tapid) * 128 + mi * 16) * 192 + (xoff) + k2 * 32);       \
  }

#define LOAD_BF(set, a, o, xoff)                                               \
  {                                                                            \
    _Pragma("unroll") for (int k2 = 0; k2 < 2; ++k2)                           \
      _Pragma("unroll") for (int ti = 0; ti < 4; ++ti)                         \
        bfr[set][k2][ti] = *(const bf16x8*)(xlane +                            \
            (ti * 16 + (o) - (a) * 66) * 192 + (xoff) + k2 * 32);              \
  }

__global__ __launch_bounds__(256, 1) void convt_mfma(
    const unsigned short* __restrict__ xt, const unsigned short* __restrict__ wt,
    const float* __restrict__ bias, const unsigned char* __restrict__ many,
    float* __restrict__ out) {
  const int tid = threadIdx.x, lane = tid & 63, wv = tid >> 6;
  const int l15 = lane & 15, kc = lane >> 4;
  const int coh = wv & 1, oys = wv >> 1;
  // XCD swizzle: 256 blocks = 8 XCD x 32; each XCD works one batch image.
  const int sw = (blockIdx.x & 7) * 32 + (blockIdx.x >> 3);
  const int b = sw >> 5, oyq = sw & 31;
  const int oy = oyq * 2 + oys;

  // per-lane fragment bases (element units)
  const unsigned short* xlane = xt + ((size_t)(b * 66 + oy + 2) * 66 + l15) * 192 + kc * 8;
  const unsigned short* wlane = wt + (size_t)(coh * 64 + l15) * 192 + kc * 8;

  // tap schedule grouped by (a = plane idx, o = ixm shift); 9 groups, 25 taps
  constexpr int KH[25]    = {0,1, 0,0,1,1, 0,0,1,1, 2,3, 2,2,3,3, 2,2,3,3, 4, 4,4, 4,4};
  constexpr int KW[25]    = {4,4, 2,3,2,3, 0,1,0,1, 4,4, 2,3,2,3, 0,1,0,1, 4, 2,3, 0,1};
  constexpr int GID[25]   = {0,0, 1,1,1,1, 2,2,2,2, 3,3, 4,4,4,4, 5,5,5,5, 6, 7,7, 8,8};
  constexpr int GLAST[25] = {0,1, 0,0,0,1, 0,0,0,1, 0,1, 0,0,0,1, 0,0,0,1, 1, 0,1, 0,0};
  constexpr int GA[9] = {0,0,0, 1,1,1, 2,2,2};
  constexpr int GO[9] = {0,1,2, 0,1,2, 0,1,2};

  bf16x8 afr[2][2][4];   // [set][k2][mi]
  bf16x8 bfr[2][2][4];   // [set][k2][ti]

  f32x4 acc[2][2][4][4];  // [ph][pw][mi][ti]
  #pragma unroll
  for (int p = 0; p < 2; ++p)
    #pragma unroll
    for (int q = 0; q < 2; ++q)
      #pragma unroll
      for (int i = 0; i < 4; ++i)
        #pragma unroll
        for (int j = 0; j < 4; ++j)
          acc[p][q][i][j] = (f32x4){0.f, 0.f, 0.f, 0.f};

  #pragma unroll 1
  for (int c64 = 0; c64 < 3; ++c64) {
    const int xoff = c64 * 64;            // ci64 slice offset (elements)
    LOAD_AF(0, 4 /* tap (0,4) */, xoff)   // round prologue
    LOAD_BF(0, 0, 0, xoff)
    #pragma unroll
    for (int t = 0; t < 25; ++t) {
      const int g = GID[t], ph = KH[t] & 1, pw = KW[t] & 1;
      if (t < 24) { LOAD_AF((t + 1) & 1, KH[t + 1] * 5 + KW[t + 1], xoff) }
      if (GLAST[t] && g < 8) { LOAD_BF((g + 1) & 1, GA[g + 1], GO[g + 1], xoff) }
      #pragma unroll
      for (int k2 = 0; k2 < 2; ++k2)
        #pragma unroll
        for (int mi = 0; mi < 4; ++mi)
          #pragma unroll
          for (int ti = 0; ti < 4; ++ti)
            acc[ph][pw][mi][ti] = __builtin_amdgcn_mfma_f32_16x16x32_bf16(
                afr[t & 1][k2][mi], bfr[g & 1][k2][ti], acc[ph][pw][mi][ti], 0, 0, 0);
    }
  }

  // ---- epilogue: fuse parities per lane -> coalesced f32x2 stores ----
  #pragma unroll
  for (int mi = 0; mi < 4; ++mi) {
    const f32x4 bv = *(const f32x4*)(bias + coh * 64 + mi * 16 + kc * 4);
    #pragma unroll
    for (int ph = 0; ph < 2; ++ph) {
      const int oh = 2 * oy + ph;
      #pragma unroll
      for (int ti = 0; ti < 4; ++ti) {
        const int ow0 = (ti * 16 + l15) * 2;
        const unsigned short m2 =
            *(const unsigned short*)(many + ((size_t)b * OHH + oh) * OWW + ow0);
        #pragma unroll
        for (int r = 0; r < 4; ++r) {
          const int co = coh * 64 + mi * 16 + kc * 4 + r;
          f32x2 v;
          v.x = (m2 & 0x00FFu) ? acc[ph][0][mi][ti][r] + bv[r] : 0.f;
          v.y = (m2 & 0xFF00u) ? acc[ph][1][mi][ti][r] + bv[r] : 0.f;
          *(f32x2*)(out + (((size_t)(b * COUT + co)) * OHH + oh) * OWW + ow0) = v;
        }
      }
    }
  }
}

extern "C" void kernel_launch(void* const* d_in, const int* in_sizes, int n_in,
                              void* d_out, int out_size, void* d_ws, size_t ws_size,
                              hipStream_t stream) {
  const float* x    = (const float*)d_in[0];
  const int*   mask = (const int*)d_in[1];
  const float* w    = (const float*)d_in[2];
  const float* bias = (const float*)d_in[3];
  float* out = (float*)d_out;

  // ws: many 128KB | xt 8*66 planes bf16 (12.77MB + 4KB slack) | wt 1.23MB
  unsigned char*  many = (unsigned char*)d_ws;
  unsigned short* xt   = (unsigned short*)((char*)d_ws + 131072);
  unsigned short* wt   = (unsigned short*)((char*)d_ws + 131072 +
                                           (size_t)NB * 66 * XPLN_G * 2 + 4096);

  pool_mask_k<<<(NB * OHH * OWW + 255) / 256, 256, 0, stream>>>(mask, many);
  xpose_k<<<NB * 66, 256, 0, stream>>>(x, xt);
  wpack_k<<<(CIN * COUT + 255) / 256, 256, 0, stream>>>(w, wt);
  convt_mfma<<<256, 256, 0, stream>>>(xt, wt, bias, many, out);
}

// Round 7
// 110.888 us; speedup vs baseline: 1.3863x; 1.3863x over previous
//
#include <hip/hip_runtime.h>

// MyConvT: masked ConvTranspose2d, B=8, Cin=192, Cout=128, 64x64 -> 128x128,
// K=5, S=2, P=2, OP=1.  out = pooled_mask ? (convT(x,w) + bias) : 0
// Round 6: cache-direct, occupancy-driven. 1024 blocks = 4 parity classes x
// 256 (b,oy-pair); block = 4 waves (coh x oys); wave = 64co x 64owp x 1oy,
// acc[4][4] = 64 VGPR, single-set operands => ~110 VGPR => 4 waves/SIMD.
// Fragment-major layouts make every load a contiguous 1KB wave-load with
// SGPR base + immediate offsets. No LDS, no barriers, no asm waitcnts.

#define NB   8
#define CIN  192
#define COUT 128
#define HH   64
#define WW   64
#define OHH  128
#define OWW  128
#define MH   132
#define MW   132

// x3[b][iyH 66][q 6][ixm 66][ci 32] bf16 ; plane elems (per iyH) = 6*66*32
#define X3_PLANE 12672
// w3[tap 25][q 6][co 128][ci 32] bf16

typedef short bf16x8 __attribute__((ext_vector_type(8)));
typedef float f32x4  __attribute__((ext_vector_type(4)));

static __device__ __forceinline__ unsigned short f2bf(float f) {
  union { float f; unsigned int u; } a; a.f = f;
  return (unsigned short)((a.u + 0x7fffu + ((a.u >> 16) & 1u)) >> 16);   // RNE
}

// ---------------- mask 5x5 any-pool -> byte map [B][OH][OW] ----------------
__global__ __launch_bounds__(256) void pool_mask_k(const int* __restrict__ mask,
                                                   unsigned char* __restrict__ many) {
  int idx = blockIdx.x * 256 + threadIdx.x;
  if (idx >= NB * OHH * OWW) return;
  int ow = idx & (OWW - 1);
  int oh = (idx >> 7) & (OHH - 1);
  int b  = idx >> 14;
  const int* mp = mask + (b * MH + oh) * MW + ow;
  int any = 0;
  #pragma unroll
  for (int i = 0; i < 5; ++i)
    #pragma unroll
    for (int j = 0; j < 5; ++j)
      any |= mp[i * MW + j];
  many[idx] = (any != 0) ? 1 : 0;
}

// x transpose: [b][ci][iy][ix] f32 -> x3[b][iyH][q][ixm][ci32] bf16
// iyH = iy+1 (planes 0,65 zero halo); ixm = ix+1 (rows 0,65 zero halo).
__global__ __launch_bounds__(256) void xpose_k(const float* __restrict__ x,
                                               unsigned short* __restrict__ x3) {
  const int b = blockIdx.x / 66, iyH = blockIdx.x % 66;
  const int lane = threadIdx.x & 63, wv = threadIdx.x >> 6;
  unsigned short* pl = x3 + (size_t)(b * 66 + iyH) * X3_PLANE;

  if (iyH == 0 || iyH == 65) {                       // zero halo plane
    for (int i = threadIdx.x; i < X3_PLANE / 8; i += 256)
      *(uint4*)(pl + i * 8) = make_uint4(0, 0, 0, 0);
    return;
  }
  const int iy = iyH - 1;
  if (threadIdx.x < 48) {                            // zero halo rows per q
    int row = threadIdx.x >> 2;                      // 0..11 -> (q, ixm 0|65)
    int q = row >> 1, ixm = (row & 1) * 65, ch = threadIdx.x & 3;
    *(uint4*)(pl + ((size_t)q * 66 + ixm) * 32 + ch * 8) = make_uint4(0, 0, 0, 0);
  }
  #pragma unroll
  for (int k = 0; k < 6; ++k) {
    int ci0 = wv * 48 + k * 8;
    int q = ci0 >> 5, c = ci0 & 31;
    unsigned short p[8];
    #pragma unroll
    for (int e = 0; e < 8; ++e)
      p[e] = f2bf(x[(((size_t)b * CIN + ci0 + e) * HH + iy) * WW + lane]);
    uint4 v;
    v.x = (unsigned)p[0] | ((unsigned)p[1] << 16);
    v.y = (unsigned)p[2] | ((unsigned)p[3] << 16);
    v.z = (unsigned)p[4] | ((unsigned)p[5] << 16);
    v.w = (unsigned)p[6] | ((unsigned)p[7] << 16);
    *(uint4*)(pl + ((size_t)q * 66 + 1 + lane) * 32 + c) = v;
  }
}

// w repack: [ci][co][kh][kw] f32 -> w3[tap][q][co][ci32] bf16
__global__ __launch_bounds__(256) void wpack_k(const float* __restrict__ w,
                                               unsigned short* __restrict__ w3) {
  int idx = blockIdx.x * 256 + threadIdx.x;          // 24576 threads
  int c = idx & 31, co = (idx >> 5) & 127, q = idx >> 12;
  int ci = q * 32 + c;
  const float* src = w + (size_t)(ci * COUT + co) * 25;
  #pragma unroll
  for (int tap = 0; tap < 25; ++tap)
    w3[((size_t)(tap * 6 + q) * COUT + co) * 32 + c] = f2bf(src[tap]);
}

// ------------------------------ main kernel --------------------------------
template<int PH, int PW>
__device__ __forceinline__ void conv_cls(
    const unsigned short* __restrict__ x3, const unsigned short* __restrict__ w3,
    const float* __restrict__ bias, const unsigned char* __restrict__ many,
    float* __restrict__ out, int gid) {
  constexpr int NKK = PH ? 2 : 3;
  constexpr int NKW = PW ? 2 : 3;
  const int tid = threadIdx.x, lane = tid & 63, wv = tid >> 6;
  const int l15 = lane & 15, kc = lane >> 4;
  const int coh = wv & 1, oys = wv >> 1;
  // XCD-chunk: gid&7 = XCD; all 32 blocks of an XCD share batch image b.
  const int sw = (gid & 7) * 32 + (gid >> 3);
  const int b = sw >> 5, oyq = sw & 31, oy = oyq * 2 + oys;
  const int voff = l15 * 64 + kc * 16;               // bytes within 1KB fragment

  f32x4 acc[4][4];
  #pragma unroll
  for (int i = 0; i < 4; ++i)
    #pragma unroll
    for (int j = 0; j < 4; ++j)
      acc[i][j] = (f32x4){0.f, 0.f, 0.f, 0.f};

  const char* wB = (const char*)w3 + voff + coh * 4096;
  const char* xB = (const char*)x3 + voff;

  #pragma unroll 1
  for (int q = 0; q < 6; ++q) {
    const char* wq = wB + q * 8192;
    #pragma unroll
    for (int kk = 0; kk < NKK; ++kk) {
      const int iyH = oy + 2 - kk;
      const char* xq = xB + (size_t)((b * 66 + iyH) * 6 + q) * 4224;
      #pragma unroll
      for (int kj = 0; kj < NKW; ++kj) {
        const int tap = (PH + 2 * kk) * 5 + PW + 2 * kj;
        const char* ap = wq + (size_t)tap * 49152;
        const char* bp = xq + (2 - kj) * 64;
        bf16x8 af[4], bf[4];
        #pragma unroll
        for (int mi = 0; mi < 4; ++mi) af[mi] = *(const bf16x8*)(ap + mi * 1024);
        #pragma unroll
        for (int ti = 0; ti < 4; ++ti) bf[ti] = *(const bf16x8*)(bp + ti * 1024);
        #pragma unroll
        for (int mi = 0; mi < 4; ++mi)
          #pragma unroll
          for (int ti = 0; ti < 4; ++ti)
            acc[mi][ti] = __builtin_amdgcn_mfma_f32_16x16x32_bf16(
                af[mi], bf[ti], acc[mi][ti], 0, 0, 0);
      }
    }
  }

  // ---- epilogue: bias + mask fused, direct register stores ----
  const int oh = 2 * oy + PH;
  const unsigned char* mrow = many + ((size_t)b * OHH + oh) * OWW + PW;
  unsigned char mb[4];
  #pragma unroll
  for (int ti = 0; ti < 4; ++ti) mb[ti] = mrow[2 * (ti * 16 + l15)];
  float* ob = out + (((size_t)(b * COUT + coh * 64)) * OHH + oh) * OWW + PW;
  #pragma unroll
  for (int mi = 0; mi < 4; ++mi) {
    const f32x4 bv = *(const f32x4*)(bias + coh * 64 + mi * 16 + kc * 4);
    #pragma unroll
    for (int r = 0; r < 4; ++r) {
      const int co_off = mi * 16 + kc * 4 + r;
      float* orow = ob + (size_t)co_off * (OHH * OWW);
      #pragma unroll
      for (int ti = 0; ti < 4; ++ti)
        orow[2 * (ti * 16 + l15)] = mb[ti] ? acc[mi][ti][r] + bv[r] : 0.f;
    }
  }
}

// grid 1024: class = bid>>8 (each CU hosts all 4 classes of one gid =>
// 75 tap-steps/CU, perfectly balanced; classes share x in L1/L2 and their
// complementary stride-2 stores merge in the same XCD L2).
__global__ __launch_bounds__(256, 4) void convt_mfma(
    const unsigned short* __restrict__ x3, const unsigned short* __restrict__ w3,
    const float* __restrict__ bias, const unsigned char* __restrict__ many,
    float* __restrict__ out) {
  const int cls = blockIdx.x >> 8, gid = blockIdx.x & 255;
  if      (cls == 0) conv_cls<0, 0>(x3, w3, bias, many, out, gid);
  else if (cls == 1) conv_cls<0, 1>(x3, w3, bias, many, out, gid);
  else if (cls == 2) conv_cls<1, 0>(x3, w3, bias, many, out, gid);
  else               conv_cls<1, 1>(x3, w3, bias, many, out, gid);
}

extern "C" void kernel_launch(void* const* d_in, const int* in_sizes, int n_in,
                              void* d_out, int out_size, void* d_ws, size_t ws_size,
                              hipStream_t stream) {
  const float* x    = (const float*)d_in[0];
  const int*   mask = (const int*)d_in[1];
  const float* w    = (const float*)d_in[2];
  const float* bias = (const float*)d_in[3];
  float* out = (float*)d_out;

  // ws: many 128KB | x3 13.38MB | w3 1.23MB  (~14.7MB)
  unsigned char*  many = (unsigned char*)d_ws;
  unsigned short* x3   = (unsigned short*)((char*)d_ws + 131072);
  unsigned short* w3   = (unsigned short*)((char*)d_ws + 131072 +
                                           (size_t)NB * 66 * X3_PLANE * 2);

  pool_mask_k<<<(NB * OHH * OWW + 255) / 256, 256, 0, stream>>>(mask, many);
  xpose_k<<<NB * 66, 256, 0, stream>>>(x, x3);
  wpack_k<<<(CIN * COUT) / 256, 256, 0, stream>>>(w, w3);
  convt_mfma<<<1024, 256, 0, stream>>>(x3, w3, bias, many, out);
}